// Round 8
// baseline (262.861 us; speedup 1.0000x reference)
//
#include <hip/hip_runtime.h>

typedef __fp16 h2 __attribute__((ext_vector_type(2)));
typedef unsigned int u32;
typedef unsigned short u16;

#define NPTS 1600
#define NCHUNK 10
#define CHUNKJ 160
#define TILE 32
// softmax scale * log2e folded into Q
#define QS (0.35355339059327373f*1.4426950408889634f)
// 1/(sqrt(2)*6)
#define PSCALE 0.11785113019775793f
#define LOG2E 1.4426950408889634f

__device__ __forceinline__ float leaky(float x){ return x >= 0.f ? x : 0.2f*x; }
__device__ __forceinline__ float d4(float4 a, float4 b){ return a.x*b.x + a.y*b.y + a.z*b.z + a.w*b.w; }
__device__ __forceinline__ u32 pkn(float a, float b){ h2 v; v[0]=(__fp16)a; v[1]=(__fp16)b; return __builtin_bit_cast(u32,v); }
__device__ __forceinline__ h2 u2h(u32 u){ return __builtin_bit_cast(h2,u); }
__device__ __forceinline__ float dot2(h2 a, h2 b, float c){ return __builtin_amdgcn_fdot2(a,b,c,false); }
__device__ __forceinline__ u32 rfl(u32 x){ return (u32)__builtin_amdgcn_readfirstlane((int)x); }

// ---------------- K1: input MLP + group stats partials + weight packing ----------------
__global__ __launch_bounds__(256) void k_in(
    const float* __restrict__ feat, const float* __restrict__ w1, const float* __restrict__ b1,
    const float* __restrict__ w2, const float* __restrict__ b2,
    const float* __restrict__ conv_w1, const float* __restrict__ conv_b1,
    const float* __restrict__ conv_w2,
    const float* __restrict__ rbf_a, const float* __restrict__ rbf_b,
    const float* __restrict__ rbf_ls, const float* __restrict__ rbf_c,
    float* __restrict__ h2out, float* __restrict__ bstat1, float* __restrict__ wpk)
{
  __shared__ float sh[4][64];
  __shared__ float sred[4][8];
  int t = threadIdx.x, w = t>>6, c = t&63;
  int i = blockIdx.x*4 + w;

  if (blockIdx.x == 0) {
    u32* wp = (u32*)wpk;
    { // w2 packed f16: 64 rows x 4 u32
      int row = t>>2, q = t&3;
      wp[32 + row*4 + q] = pkn(conv_w2[row*8+2*q], conv_w2[row*8+2*q+1]);
    }
    if (t < 32) { // folded rbf weights: wrg = conv_w1[:,4:8] @ rbf_a
      int cc = t>>2, kq = t&3;
      float a0=0.f, a1=0.f;
      #pragma unroll
      for (int p=0;p<4;p++){ a0 += conv_w1[cc*8+4+p]*rbf_a[p*8+2*kq]; a1 += conv_w1[cc*8+4+p]*rbf_a[p*8+2*kq+1]; }
      wp[cc*4+kq] = pkn(a0,a1);
    } else if (t < 40) { // b1' = conv_b1 + conv_w1[:,4:8] @ rbf_b
      int cc = t-32; float s = conv_b1[cc];
      #pragma unroll
      for (int p=0;p<4;p++) s += conv_w1[cc*8+4+p]*rbf_b[p];
      wpk[288+cc] = s;
    } else if (t == 40) { // rbf coefficients: R[k]=E*U^k*A^(k^2), A const
      float sig = fmaxf(expf(rbf_ls[0]), 1e-6f);
      float m = -LOG2E/(2.f*sig*sig);
      float c0 = rbf_c[0];
      float dl = rbf_c[1] - rbf_c[0];
      float A1v = m*dl*dl;
      wpk[296] = c0;
      wpk[297] = m;
      wpk[298] = -2.f*m*dl;        // C2 (per-pair: U = exp2(C2*g0))
      wpk[299] = A1v;
      float Av = exp2f(A1v);
      wpk[300] = Av;               // A
      wpk[301] = Av*Av;            // A^2
    }
  }

  const float4* f4 = (const float4*)(feat + i*16);
  float4 f0=f4[0], f1v=f4[1], f2v=f4[2], f3v=f4[3];
  const float4* w1r = (const float4*)(w1 + c*16);
  float h1 = b1[c] + d4(f0,w1r[0]) + d4(f1v,w1r[1]) + d4(f2v,w1r[2]) + d4(f3v,w1r[3]);
  h1 = leaky(h1);
  sh[w][c] = h1;
  __syncthreads();
  float hh = b2[c];
  #pragma unroll
  for (int k4=0;k4<16;k4++){
    float4 hv = *(const float4*)&sh[w][k4*4];
    hh += d4(hv, *(const float4*)&w2[c*64 + k4*4]);
  }
  hh = leaky(hh);
  h2out[i*64+c] = hh;

  float s = hh, qq = hh*hh;
  s += __shfl_xor(s,1);  qq += __shfl_xor(qq,1);
  s += __shfl_xor(s,2);  qq += __shfl_xor(qq,2);
  s += __shfl_xor(s,4);  qq += __shfl_xor(qq,4);
  s += __shfl_xor(s,8);  qq += __shfl_xor(qq,8);
  if ((c&15)==0){ int g=c>>4; sred[w][g]=s; sred[w][4+g]=qq; }
  __syncthreads();
  if (t<8) bstat1[blockIdx.x*8+t] = sred[0][t]+sred[1][t]+sred[2][t]+sred[3][t];
}

// ---------------- K2: reduce stats, group-norm, packed Q/K/V + PN ----------------
__global__ __launch_bounds__(256) void k_qkv(
  const float* __restrict__ h2b, const float* __restrict__ bstat1,
  const float* __restrict__ g_in, const float* __restrict__ be_in,
  const float* __restrict__ wq, const float* __restrict__ bq,
  const float* __restrict__ wk, const float* __restrict__ bk,
  const float* __restrict__ wv, const float* __restrict__ bv,
  const float* __restrict__ pts, const float* __restrict__ nuv,
  u32* __restrict__ Q16, u32* __restrict__ K16, u32* __restrict__ V16,
  float* __restrict__ PN)
{
  __shared__ float sh[4][64];
  __shared__ float sp[64];
  __shared__ float sst[8];
  int t=threadIdx.x, w=t>>6, c=t&63;
  int i = blockIdx.x*4 + w;
  if (t<64){ int g=t&7; float s=0.f;
    for (int m=t>>3; m<400; m+=8) s += bstat1[m*8+g];
    sp[t]=s; }
  __syncthreads();
  if (t<8){ float s=0.f;
    #pragma unroll
    for (int q=0;q<8;q++) s += sp[q*8+t];
    sst[t]=s; }
  __syncthreads();
  int g = c>>4;
  const float inv = 1.f/25600.f;
  float mu = sst[g]*inv;
  float var = sst[4+g]*inv - mu*mu;
  float rs = rsqrtf(var + 1e-5f);
  float hn = (h2b[i*64+c]-mu)*rs*g_in[c] + be_in[c];
  sh[w][c] = hn;
  __syncthreads();
  float q=bq[c], k=bk[c], v=bv[c];
  #pragma unroll
  for (int k4=0;k4<16;k4++){
    float4 hv = *(const float4*)&sh[w][k4*4];
    q += d4(hv, *(const float4*)&wq[c*64+k4*4]);
    k += d4(hv, *(const float4*)&wk[c*64+k4*4]);
    v += d4(hv, *(const float4*)&wv[c*64+k4*4]);
  }
  // packed outputs
  u16* Q16u = (u16*)Q16;
  u16* K16u = (u16*)K16;
  u16* V16u = (u16*)V16;
  __fp16 qh = (__fp16)(q*QS);
  __fp16 kh = (__fp16)k;
  __fp16 vh = (__fp16)v;
  Q16u[i*64 + c] = __builtin_bit_cast(u16, qh);
  K16u[i*64 + c] = __builtin_bit_cast(u16, kh);
  int pr = ((i>>5)<<4) + (i&15);   // pair row: (j, j+16) within 32-group
  int hf = (i>>4)&1;
  V16u[(pr*64 + c)*2 + hf] = __builtin_bit_cast(u16, vh);
  if (c < 6){
    float pv = (c<3) ? pts[i*3+c]*PSCALE : nuv[i*9+(c-3)];
    PN[i*8+c] = pv;
  } else if (c < 8) PN[i*8+c] = 0.f;
}

// ---------------- K3: all-pairs kernel — 2 head-passes, acc[32], barrier-free main loop ----------------
__global__ __launch_bounds__(256) void k_pair(
  const u32* __restrict__ Q16, const u32* __restrict__ K16, const u32* __restrict__ V16,
  const float* __restrict__ PN, const float* __restrict__ nuv,
  const float* __restrict__ w1, const float* __restrict__ wpk,
  const float* __restrict__ b2g, float* __restrict__ part)
{
  __shared__ __align__(16) u32   sQ16[16*36];
  __shared__ __align__(16) u32   sWX[16*20];
  __shared__ __align__(16) float sRedH[4*16*36];

  int t = threadIdx.x;
  int r = t & 15, jl = t >> 4;
  int bx = blockIdx.x;
  int rb = bx % 100, jc = bx / 100;
  int I0 = rb*16, J0 = jc*CHUNKJ;
  int i = I0 + r;

  if (t < 128) { // stage Q16 tile: 16x32 u32
    int qrow = t>>3, qq4 = (t&7)<<2;
    *(uint4*)&sQ16[qrow*36+qq4] = *(const uint4*)&Q16[(I0+qrow)*32+qq4];
  }
  if (t < 128) { // wx[c][:] = conv_w1[c,0:3] @ nuv[i] ; last = conv_w1[c,3]
    int r2 = t>>3, cc = t&7, ib = (I0+r2)*9;
    float a0=w1[cc*8], a1=w1[cc*8+1], a2=w1[cc*8+2];
    float x = a0*nuv[ib+0] + a1*nuv[ib+3] + a2*nuv[ib+6];
    float y = a0*nuv[ib+1] + a1*nuv[ib+4] + a2*nuv[ib+7];
    float z = a0*nuv[ib+2] + a1*nuv[ib+5] + a2*nuv[ib+8];
    sWX[r2*20+cc*2+0] = pkn(x,y);
    sWX[r2*20+cc*2+1] = pkn(z, w1[cc*8+3]);
  }
  __syncthreads();

  const u32* wp = (const u32*)wpk;
  h2 wr[8][4];   // wave-uniform -> SGPRs via readfirstlane
  #pragma unroll
  for (int cc=0;cc<8;cc++)
    #pragma unroll
    for (int q2=0;q2<4;q2++) wr[cc][q2] = u2h(rfl(wp[cc*4+q2]));
  const u32* w2p = wp + 32;
  const float* b1p = wpk + 288;
  float c0  = wpk[296];
  float mco = wpk[297];
  float C2  = wpk[298];
  float Af  = wpk[300];
  float A2f = wpk[301];

  float4 pni0 = *(const float4*)&PN[i*8];
  float4 pni1 = *(const float4*)&PN[i*8+4];
  float pix = pni0.x, piy = pni0.y, piz = pni0.z;
  float nix = pni0.w, niy = pni1.x, niz = pni1.y;

  #pragma unroll 1
  for (int hp=0; hp<2; hp++) {
    float acc[32];
    #pragma unroll
    for (int o=0;o<32;o++) acc[o] = 0.f;
    float lh[4] = {0.f,0.f,0.f,0.f};

    #pragma unroll 1
    for (int tb=0; tb<CHUNKJ; tb+=TILE) {
      int jbase = J0 + tb;
      int jA = jbase + jl;
      int jB = jA + 16;

      h2 F1p[2][4];
      float Wv[2];
      #pragma unroll
      for (int jj=0;jj<2;jj++) {
        int j = jj ? jB : jA;
        float4 a0 = *(const float4*)&PN[j*8];
        float4 a1 = *(const float4*)&PN[j*8+4];
        float dx = a0.x-pix, dy = a0.y-piy, dz = a0.z-piz;
        float ndot = nix*a0.w + niy*a1.x + niz*a1.y;
        float d2r = dx*dx + dy*dy + dz*dz;
        float wf = 2.f - ndot;
        float d2 = d2r*wf*wf;
        float tp = fmaf(d2, 0.3333333333333333f, 1.f);
        Wv[jj] = __builtin_amdgcn_rcpf(tp*tp*tp);     // (1+d2/3)^-3
        float dd = __builtin_amdgcn_sqrtf(d2);
        float g0 = dd - c0;
        float E = __builtin_amdgcn_exp2f(mco*g0*g0);
        float U = __builtin_amdgcn_exp2f(C2*g0);
        float R[8];
        R[0] = E;
        float tt = U*Af;
        #pragma unroll
        for (int k=1;k<8;k++){ R[k] = R[k-1]*tt; tt *= A2f; }
        h2 xv0; xv0[0]=(__fp16)dx; xv0[1]=(__fp16)dy;
        h2 xv1; xv1[0]=(__fp16)dz; xv1[1]=(__fp16)ndot;
        h2 r01=__builtin_amdgcn_cvt_pkrtz(R[0],R[1]);
        h2 r23=__builtin_amdgcn_cvt_pkrtz(R[2],R[3]);
        h2 r45=__builtin_amdgcn_cvt_pkrtz(R[4],R[5]);
        h2 r67=__builtin_amdgcn_cvt_pkrtz(R[6],R[7]);
        float F1f[8];
        #pragma unroll
        for (int cc=0;cc<8;cc++){
          uint2 wx2 = *(const uint2*)&sWX[r*20+cc*2];
          float fa = dot2(r01, wr[cc][0], dot2(r23, wr[cc][1], b1p[cc]));
          float fb = dot2(r45, wr[cc][2], dot2(r67, wr[cc][3], 0.f));
          float fc = dot2(u2h(wx2.x), xv0, dot2(u2h(wx2.y), xv1, 0.f));
          F1f[cc] = fmaxf(fa+fb+fc, 0.f);
        }
        F1p[jj][0]=__builtin_amdgcn_cvt_pkrtz(F1f[0],F1f[1]);
        F1p[jj][1]=__builtin_amdgcn_cvt_pkrtz(F1f[2],F1f[3]);
        F1p[jj][2]=__builtin_amdgcn_cvt_pkrtz(F1f[4],F1f[5]);
        F1p[jj][3]=__builtin_amdgcn_cvt_pkrtz(F1f[6],F1f[7]);
      }
      h2 Wvp = __builtin_amdgcn_cvt_pkrtz(Wv[0], Wv[1]);

      const u32* kArow = &K16[jA*32];
      const u32* kBrow = &K16[jB*32];
      const u32* vrow  = &V16[(((u32)jbase>>1)+jl)*64];

      #pragma unroll
      for (int hh=0; hh<4; hh++) {
        int h = (hp<<2) + hh;
        uint4 qh = *(const uint4*)&sQ16[r*36 + (h<<2)];
        uint4 kA = *(const uint4*)&kArow[h<<2];
        uint4 kB = *(const uint4*)&kBrow[h<<2];
        float S0 = dot2(u2h(qh.x),u2h(kA.x), dot2(u2h(qh.y),u2h(kA.y), 0.f))
                 + dot2(u2h(qh.z),u2h(kA.z), dot2(u2h(qh.w),u2h(kA.w), 0.f));
        float S1 = dot2(u2h(qh.x),u2h(kB.x), dot2(u2h(qh.y),u2h(kB.y), 0.f))
                 + dot2(u2h(qh.z),u2h(kB.z), dot2(u2h(qh.w),u2h(kB.w), 0.f));
        float e0 = __builtin_amdgcn_exp2f(S0);
        float e1 = __builtin_amdgcn_exp2f(S1);
        lh[hh] += e0 + e1;
        h2 ewp = __builtin_amdgcn_cvt_pkrtz(e0,e1) * Wvp;
        uint4 vpA = *(const uint4*)&vrow[h*8];
        uint4 vpB = *(const uint4*)&vrow[h*8+4];
        u32 vparr[8] = {vpA.x,vpA.y,vpA.z,vpA.w,vpB.x,vpB.y,vpB.z,vpB.w};
        #pragma unroll
        for (int cc=0;cc<8;cc++){
          int rw = h*8+cc;
          h2 w0=u2h(w2p[rw*4+0]), w1h=u2h(w2p[rw*4+1]), w2h=u2h(w2p[rw*4+2]), w3h=u2h(w2p[rw*4+3]);
          float b2v = b2g[rw];
          float fh0 = dot2(F1p[0][0],w0, dot2(F1p[0][1],w1h, b2v))
                    + dot2(F1p[0][2],w2h, dot2(F1p[0][3],w3h, 0.f));
          float fh1 = dot2(F1p[1][0],w0, dot2(F1p[1][1],w1h, b2v))
                    + dot2(F1p[1][2],w2h, dot2(F1p[1][3],w3h, 0.f));
          h2 fhp = __builtin_amdgcn_cvt_pkrtz(fmaxf(fh0,0.f), fmaxf(fh1,0.f));
          h2 ev = u2h(vparr[cc]) * ewp;
          acc[hh*8+cc] = dot2(fhp, ev, acc[hh*8+cc]);
        }
      }
    }

    // ---- epilogue for this head-pass ----
    #pragma unroll
    for (int o=0;o<32;o++){ acc[o] += __shfl_xor(acc[o],16); acc[o] += __shfl_xor(acc[o],32); }
    #pragma unroll
    for (int hh=0;hh<4;hh++){ lh[hh] += __shfl_xor(lh[hh],16); lh[hh] += __shfl_xor(lh[hh],32); }
    __syncthreads();
    int wv = t >> 6, lane = t & 63;
    if (lane < 16) {
      #pragma unroll
      for (int o=0;o<32;o++) sRedH[(wv*16+lane)*36+o] = acc[o];
      #pragma unroll
      for (int hh=0;hh<4;hh++) sRedH[(wv*16+lane)*36+32+hh] = lh[hh];
    }
    __syncthreads();
    for (int v2 = t; v2 < 16*36; v2 += 256) {
      int rr = v2/36, o = v2 - rr*36;
      float s = sRedH[(0*16+rr)*36+o]+sRedH[(1*16+rr)*36+o]+sRedH[(2*16+rr)*36+o]+sRedH[(3*16+rr)*36+o];
      int off = (o < 32) ? (hp<<5)+o : 64 + (hp<<2) + (o-32);
      part[(jc*NPTS + I0 + rr)*72 + off] = s;
    }
  }
}

// ---------------- K4: merge chunk partials, divide, output MLP, out-stat partials ----------------
__global__ __launch_bounds__(256) void k_agg(
  const float* __restrict__ part, const float* __restrict__ w_o1, const float* __restrict__ b_o1,
  const float* __restrict__ w_o2, const float* __restrict__ b_o2,
  float* __restrict__ o2b, float* __restrict__ bstat2)
{
  __shared__ float sh[4][64];
  __shared__ float sred[4][8];
  int t = threadIdx.x, w = t>>6, c = t&63;
  int i = blockIdx.x*4 + w;
  int h = c>>3;
  float a = 0.f, L = 0.f;
  #pragma unroll
  for (int jc=0;jc<NCHUNK;jc++){
    const float* p = part + (jc*NPTS + i)*72;
    a += p[c]; L += p[64+h];
  }
  float agg = a / L;
  sh[w][c] = agg; __syncthreads();
  float o1 = b_o1[c];
  #pragma unroll
  for (int k4=0;k4<16;k4++){
    float4 hv = *(const float4*)&sh[w][k4*4];
    o1 += d4(hv, *(const float4*)&w_o1[c*64+k4*4]);
  }
  o1 = leaky(o1);
  __syncthreads();
  sh[w][c] = o1; __syncthreads();
  float o2 = b_o2[c];
  #pragma unroll
  for (int k4=0;k4<16;k4++){
    float4 hv = *(const float4*)&sh[w][k4*4];
    o2 += d4(hv, *(const float4*)&w_o2[c*64+k4*4]);
  }
  o2 = leaky(o2);
  o2b[i*64+c] = o2;

  float s = o2, qq = o2*o2;
  s += __shfl_xor(s,1);  qq += __shfl_xor(qq,1);
  s += __shfl_xor(s,2);  qq += __shfl_xor(qq,2);
  s += __shfl_xor(s,4);  qq += __shfl_xor(qq,4);
  s += __shfl_xor(s,8);  qq += __shfl_xor(qq,8);
  if ((c&15)==0){ int g=c>>4; sred[w][g]=s; sred[w][4+g]=qq; }
  __syncthreads();
  if (t<8) bstat2[blockIdx.x*8+t] = sred[0][t]+sred[1][t]+sred[2][t]+sred[3][t];
}

// ---------------- K5: reduce out-stats, final group-norm + residual ----------------
__global__ __launch_bounds__(256) void k_out(
  const float* __restrict__ o2b, const float* __restrict__ bstat2,
  const float* __restrict__ g_out, const float* __restrict__ be_out,
  const float* __restrict__ feat, const float* __restrict__ w_res, const float* __restrict__ b_res,
  float* __restrict__ out)
{
  __shared__ float sp[64];
  __shared__ float sst[8];
  int t = threadIdx.x, w = t>>6, c = t&63;
  int i = blockIdx.x*4 + w;
  if (t<64){ int g=t&7; float s=0.f;
    for (int m=t>>3; m<400; m+=8) s += bstat2[m*8+g];
    sp[t]=s; }
  __syncthreads();
  if (t<8){ float s=0.f;
    #pragma unroll
    for (int q=0;q<8;q++) s += sp[q*8+t];
    sst[t]=s; }
  __syncthreads();
  int g = c>>4;
  const float inv = 1.f/25600.f;
  float mu = sst[g]*inv;
  float var = sst[4+g]*inv - mu*mu;
  float rs = rsqrtf(var + 1e-5f);
  float on = (o2b[i*64+c]-mu)*rs*g_out[c] + be_out[c];
  const float4* f4 = (const float4*)(feat + i*16);
  const float4* wr = (const float4*)(w_res + c*16);
  float res = b_res[c] + d4(f4[0],wr[0]) + d4(f4[1],wr[1]) + d4(f4[2],wr[2]) + d4(f4[3],wr[3]);
  out[i*64+c] = on + res;
}

extern "C" void kernel_launch(void* const* d_in, const int* in_sizes, int n_in,
                              void* d_out, int out_size, void* d_ws, size_t ws_size,
                              hipStream_t stream) {
  const float* points  = (const float*)d_in[0];
  const float* nuv     = (const float*)d_in[1];
  const float* feat    = (const float*)d_in[2];
  const float* w_in1   = (const float*)d_in[3];
  const float* b_in1   = (const float*)d_in[4];
  const float* w_in2   = (const float*)d_in[5];
  const float* b_in2   = (const float*)d_in[6];
  const float* g_in    = (const float*)d_in[7];
  const float* be_in   = (const float*)d_in[8];
  const float* wq      = (const float*)d_in[9];
  const float* bq      = (const float*)d_in[10];
  const float* wk      = (const float*)d_in[11];
  const float* bk      = (const float*)d_in[12];
  const float* wv      = (const float*)d_in[13];
  const float* bv      = (const float*)d_in[14];
  const float* conv_w1 = (const float*)d_in[15];
  const float* conv_b1 = (const float*)d_in[16];
  const float* conv_w2 = (const float*)d_in[17];
  const float* conv_b2 = (const float*)d_in[18];
  const float* rbf_ls  = (const float*)d_in[19];
  const float* rbf_a   = (const float*)d_in[20];
  const float* rbf_b   = (const float*)d_in[21];
  const float* rbf_c   = (const float*)d_in[22];
  const float* w_o1    = (const float*)d_in[23];
  const float* b_o1    = (const float*)d_in[24];
  const float* w_o2    = (const float*)d_in[25];
  const float* b_o2    = (const float*)d_in[26];
  const float* g_out   = (const float*)d_in[27];
  const float* be_out  = (const float*)d_in[28];
  const float* w_res   = (const float*)d_in[29];
  const float* b_res   = (const float*)d_in[30];

  float* ws     = (float*)d_ws;
  float* h2f    = ws;                 // 102400
  u32*   Q16    = (u32*)(ws + 102400);// 51200 u32
  u32*   K16    = (u32*)(ws + 153600);// 51200 u32
  u32*   V16    = (u32*)(ws + 204800);// 51200 u32
  float* PN     = ws + 256000;        // 12800
  float* bstat1 = ws + 268800;        // 3200
  float* bstat2 = ws + 272000;        // 3200
  float* wpk    = ws + 275200;        // 320
  float* part   = ws + 275520;        // 1152000
  float* o2b    = ws + 1427520;       // 102400
  float* out    = (float*)d_out;

  k_in<<<400, 256, 0, stream>>>(feat, w_in1, b_in1, w_in2, b_in2,
                                conv_w1, conv_b1, conv_w2, rbf_a, rbf_b, rbf_ls, rbf_c,
                                h2f, bstat1, wpk);
  k_qkv<<<400, 256, 0, stream>>>(h2f, bstat1, g_in, be_in, wq, bq, wk, bk, wv, bv,
                                 points, nuv, Q16, K16, V16, PN);
  k_pair<<<1000, 256, 0, stream>>>(Q16, K16, V16, PN, nuv, conv_w1, wpk, conv_b2, part);
  k_agg<<<400, 256, 0, stream>>>(part, w_o1, b_o1, w_o2, b_o2, o2b, bstat2);
  k_out<<<400, 256, 0, stream>>>(o2b, bstat2, g_out, be_out, feat, w_res, b_res, out);
}

// Round 9
// 258.290 us; speedup vs baseline: 1.0177x; 1.0177x over previous
//
#include <hip/hip_runtime.h>

typedef __fp16 h2 __attribute__((ext_vector_type(2)));
typedef unsigned int u32;
typedef unsigned short u16;

#define NPTS 1600
#define NCHUNK 5
#define CHUNKJ 320
#define TILE 64
// softmax scale * log2e folded into Q
#define QS (0.35355339059327373f*1.4426950408889634f)
// 1/(sqrt(2)*6)
#define PSCALE 0.11785113019775793f
#define LOG2E 1.4426950408889634f

__device__ __forceinline__ float leaky(float x){ return x >= 0.f ? x : 0.2f*x; }
__device__ __forceinline__ float d4(float4 a, float4 b){ return a.x*b.x + a.y*b.y + a.z*b.z + a.w*b.w; }
__device__ __forceinline__ u32 pkn(float a, float b){ h2 v; v[0]=(__fp16)a; v[1]=(__fp16)b; return __builtin_bit_cast(u32,v); }
__device__ __forceinline__ h2 u2h(u32 u){ return __builtin_bit_cast(h2,u); }
__device__ __forceinline__ float dot2(h2 a, h2 b, float c){ return __builtin_amdgcn_fdot2(a,b,c,false); }
__device__ __forceinline__ u32 rfl(u32 x){ return (u32)__builtin_amdgcn_readfirstlane((int)x); }

// ---------------- K1: input MLP + group stats partials + weight packing ----------------
__global__ __launch_bounds__(256) void k_in(
    const float* __restrict__ feat, const float* __restrict__ w1, const float* __restrict__ b1,
    const float* __restrict__ w2, const float* __restrict__ b2,
    const float* __restrict__ conv_w1, const float* __restrict__ conv_b1,
    const float* __restrict__ conv_w2,
    const float* __restrict__ rbf_a, const float* __restrict__ rbf_b,
    const float* __restrict__ rbf_ls, const float* __restrict__ rbf_c,
    float* __restrict__ h2out, float* __restrict__ bstat1, float* __restrict__ wpk)
{
  __shared__ float sh[4][64];
  __shared__ float sred[4][8];
  int t = threadIdx.x, w = t>>6, c = t&63;
  int i = blockIdx.x*4 + w;

  if (blockIdx.x == 0) {
    u32* wp = (u32*)wpk;
    { // w2 packed f16: 64 rows x 4 u32
      int row = t>>2, q = t&3;
      wp[32 + row*4 + q] = pkn(conv_w2[row*8+2*q], conv_w2[row*8+2*q+1]);
    }
    if (t < 32) { // folded rbf weights: wrg = conv_w1[:,4:8] @ rbf_a
      int cc = t>>2, kq = t&3;
      float a0=0.f, a1=0.f;
      #pragma unroll
      for (int p=0;p<4;p++){ a0 += conv_w1[cc*8+4+p]*rbf_a[p*8+2*kq]; a1 += conv_w1[cc*8+4+p]*rbf_a[p*8+2*kq+1]; }
      wp[cc*4+kq] = pkn(a0,a1);
    } else if (t < 40) { // b1' = conv_b1 + conv_w1[:,4:8] @ rbf_b
      int cc = t-32; float s = conv_b1[cc];
      #pragma unroll
      for (int p=0;p<4;p++) s += conv_w1[cc*8+4+p]*rbf_b[p];
      wpk[288+cc] = s;
    } else if (t == 40) { // rbf coefficients: R[k]=E*U^k*A^(k^2), A const
      float sig = fmaxf(expf(rbf_ls[0]), 1e-6f);
      float m = -LOG2E/(2.f*sig*sig);
      float c0 = rbf_c[0];
      float dl = rbf_c[1] - rbf_c[0];
      float A1v = m*dl*dl;
      wpk[296] = c0;
      wpk[297] = m;
      wpk[298] = -2.f*m*dl;        // C2 (per-pair: U = exp2(C2*g0))
      wpk[299] = A1v;
      float Av = exp2f(A1v);
      wpk[300] = Av;               // A
      wpk[301] = Av*Av;            // A^2
    }
  }

  const float4* f4 = (const float4*)(feat + i*16);
  float4 f0=f4[0], f1v=f4[1], f2v=f4[2], f3v=f4[3];
  const float4* w1r = (const float4*)(w1 + c*16);
  float h1 = b1[c] + d4(f0,w1r[0]) + d4(f1v,w1r[1]) + d4(f2v,w1r[2]) + d4(f3v,w1r[3]);
  h1 = leaky(h1);
  sh[w][c] = h1;
  __syncthreads();
  float hh = b2[c];
  #pragma unroll
  for (int k4=0;k4<16;k4++){
    float4 hv = *(const float4*)&sh[w][k4*4];
    hh += d4(hv, *(const float4*)&w2[c*64 + k4*4]);
  }
  hh = leaky(hh);
  h2out[i*64+c] = hh;

  float s = hh, qq = hh*hh;
  s += __shfl_xor(s,1);  qq += __shfl_xor(qq,1);
  s += __shfl_xor(s,2);  qq += __shfl_xor(qq,2);
  s += __shfl_xor(s,4);  qq += __shfl_xor(qq,4);
  s += __shfl_xor(s,8);  qq += __shfl_xor(qq,8);
  if ((c&15)==0){ int g=c>>4; sred[w][g]=s; sred[w][4+g]=qq; }
  __syncthreads();
  if (t<8) bstat1[blockIdx.x*8+t] = sred[0][t]+sred[1][t]+sred[2][t]+sred[3][t];
}

// ---------------- K2: reduce stats, group-norm, packed Q/K/V + PN ----------------
__global__ __launch_bounds__(256) void k_qkv(
  const float* __restrict__ h2b, const float* __restrict__ bstat1,
  const float* __restrict__ g_in, const float* __restrict__ be_in,
  const float* __restrict__ wq, const float* __restrict__ bq,
  const float* __restrict__ wk, const float* __restrict__ bk,
  const float* __restrict__ wv, const float* __restrict__ bv,
  const float* __restrict__ pts, const float* __restrict__ nuv,
  u32* __restrict__ Q16, u32* __restrict__ K16, u32* __restrict__ V16,
  float* __restrict__ PN)
{
  __shared__ float sh[4][64];
  __shared__ float sp[64];
  __shared__ float sst[8];
  int t=threadIdx.x, w=t>>6, c=t&63;
  int i = blockIdx.x*4 + w;
  if (t<64){ int g=t&7; float s=0.f;
    for (int m=t>>3; m<400; m+=8) s += bstat1[m*8+g];
    sp[t]=s; }
  __syncthreads();
  if (t<8){ float s=0.f;
    #pragma unroll
    for (int q=0;q<8;q++) s += sp[q*8+t];
    sst[t]=s; }
  __syncthreads();
  int g = c>>4;
  const float inv = 1.f/25600.f;
  float mu = sst[g]*inv;
  float var = sst[4+g]*inv - mu*mu;
  float rs = rsqrtf(var + 1e-5f);
  float hn = (h2b[i*64+c]-mu)*rs*g_in[c] + be_in[c];
  sh[w][c] = hn;
  __syncthreads();
  float q=bq[c], k=bk[c], v=bv[c];
  #pragma unroll
  for (int k4=0;k4<16;k4++){
    float4 hv = *(const float4*)&sh[w][k4*4];
    q += d4(hv, *(const float4*)&wq[c*64+k4*4]);
    k += d4(hv, *(const float4*)&wk[c*64+k4*4]);
    v += d4(hv, *(const float4*)&wv[c*64+k4*4]);
  }
  // packed outputs
  u16* Q16u = (u16*)Q16;
  u16* K16u = (u16*)K16;
  u16* V16u = (u16*)V16;
  __fp16 qh = (__fp16)(q*QS);
  __fp16 kh = (__fp16)k;
  __fp16 vh = (__fp16)v;
  Q16u[i*64 + c] = __builtin_bit_cast(u16, qh);
  K16u[i*64 + c] = __builtin_bit_cast(u16, kh);
  int pr = ((i>>6)<<5) + (i&31);   // pair row: (j, j+32) within 64-group
  int hf = (i>>5)&1;
  V16u[(pr*64 + c)*2 + hf] = __builtin_bit_cast(u16, vh);
  if (c < 6){
    float pv = (c<3) ? pts[i*3+c]*PSCALE : nuv[i*9+(c-3)];
    PN[i*8+c] = pv;
  } else if (c < 8) PN[i*8+c] = 0.f;
}

// ---------------- K3: all-pairs kernel — 512-thread blocks, barrier-free main loop ----------------
__global__ __launch_bounds__(512) void k_pair(
  const u32* __restrict__ Q16, const u32* __restrict__ K16, const u32* __restrict__ V16,
  const float* __restrict__ PN, const float* __restrict__ nuv,
  const float* __restrict__ w1, const float* __restrict__ wpk,
  const float* __restrict__ b2g, float* __restrict__ part)
{
  __shared__ __align__(16) float SM[8*16*72];  // sRed [8][16][72]; head aliases sQ16+sWX
  u32* sQ16 = (u32*)SM;            // [16][36]
  u32* sWX  = (u32*)SM + 576;      // [16][20]
  float* sRed = SM;

  int t = threadIdx.x;
  int r = t & 15, jl = t >> 4;     // jl in [0,32)
  int bx = blockIdx.x;
  int rb = bx % 100, jc = bx / 100;
  int I0 = rb*16, J0 = jc*CHUNKJ;
  int i = I0 + r;

  if (t < 128) { // stage Q16 tile: 16x32 u32
    int qrow = t>>3, qq4 = (t&7)<<2;
    *(uint4*)&sQ16[qrow*36+qq4] = *(const uint4*)&Q16[(I0+qrow)*32+qq4];
  }
  if (t < 128) { // wx[c][:] = conv_w1[c,0:3] @ nuv[i] ; last = conv_w1[c,3]
    int r2 = t>>3, cc = t&7, ib = (I0+r2)*9;
    float a0=w1[cc*8], a1=w1[cc*8+1], a2=w1[cc*8+2];
    float x = a0*nuv[ib+0] + a1*nuv[ib+3] + a2*nuv[ib+6];
    float y = a0*nuv[ib+1] + a1*nuv[ib+4] + a2*nuv[ib+7];
    float z = a0*nuv[ib+2] + a1*nuv[ib+5] + a2*nuv[ib+8];
    sWX[r2*20+cc*2+0] = pkn(x,y);
    sWX[r2*20+cc*2+1] = pkn(z, w1[cc*8+3]);
  }
  __syncthreads();

  const u32* wp = (const u32*)wpk;
  h2 wr[8][4];   // wave-uniform -> scalar regs via readfirstlane
  #pragma unroll
  for (int cc=0;cc<8;cc++)
    #pragma unroll
    for (int q2=0;q2<4;q2++) wr[cc][q2] = u2h(rfl(wp[cc*4+q2]));
  const u32* w2p = wp + 32;
  const float* b1p = wpk + 288;
  float c0  = wpk[296];
  float mco = wpk[297];
  float C2  = wpk[298];
  float Af  = wpk[300];
  float A2f = wpk[301];

  float4 pni0 = *(const float4*)&PN[i*8];
  float4 pni1 = *(const float4*)&PN[i*8+4];
  float pix = pni0.x, piy = pni0.y, piz = pni0.z;
  float nix = pni0.w, niy = pni1.x, niz = pni1.y;

  float acc[64];
  #pragma unroll
  for (int o=0;o<64;o++) acc[o] = 0.f;
  float lh[8];
  #pragma unroll
  for (int h=0;h<8;h++) lh[h] = 0.f;

  #pragma unroll 1
  for (int tb=0; tb<CHUNKJ; tb+=TILE) {
    int jbase = J0 + tb;
    int jA = jbase + jl;
    int jB = jA + 32;

    h2 F1p[2][4];
    float Wv[2];
    #pragma unroll
    for (int jj=0;jj<2;jj++) {
      int j = jj ? jB : jA;
      float4 a0 = *(const float4*)&PN[j*8];
      float4 a1 = *(const float4*)&PN[j*8+4];
      float dx = a0.x-pix, dy = a0.y-piy, dz = a0.z-piz;
      float ndot = nix*a0.w + niy*a1.x + niz*a1.y;
      float d2r = dx*dx + dy*dy + dz*dz;
      float wf = 2.f - ndot;
      float d2 = d2r*wf*wf;
      float tp = fmaf(d2, 0.3333333333333333f, 1.f);
      Wv[jj] = __builtin_amdgcn_rcpf(tp*tp*tp);     // (1+d2/3)^-3
      float dd = __builtin_amdgcn_sqrtf(d2);
      float g0 = dd - c0;
      float E = __builtin_amdgcn_exp2f(mco*g0*g0);
      float U = __builtin_amdgcn_exp2f(C2*g0);
      float R[8];
      R[0] = E;
      float tt = U*Af;
      #pragma unroll
      for (int k=1;k<8;k++){ R[k] = R[k-1]*tt; tt *= A2f; }
      h2 xv0; xv0[0]=(__fp16)dx; xv0[1]=(__fp16)dy;
      h2 xv1; xv1[0]=(__fp16)dz; xv1[1]=(__fp16)ndot;
      h2 r01=__builtin_amdgcn_cvt_pkrtz(R[0],R[1]);
      h2 r23=__builtin_amdgcn_cvt_pkrtz(R[2],R[3]);
      h2 r45=__builtin_amdgcn_cvt_pkrtz(R[4],R[5]);
      h2 r67=__builtin_amdgcn_cvt_pkrtz(R[6],R[7]);
      float F1f[8];
      #pragma unroll
      for (int cc=0;cc<8;cc++){
        uint2 wx2 = *(const uint2*)&sWX[r*20+cc*2];
        float fa = dot2(r01, wr[cc][0], dot2(r23, wr[cc][1], b1p[cc]));
        float fb = dot2(r45, wr[cc][2], dot2(r67, wr[cc][3], 0.f));
        float fc = dot2(u2h(wx2.x), xv0, dot2(u2h(wx2.y), xv1, 0.f));
        F1f[cc] = fmaxf(fa+fb+fc, 0.f);
      }
      F1p[jj][0]=__builtin_amdgcn_cvt_pkrtz(F1f[0],F1f[1]);
      F1p[jj][1]=__builtin_amdgcn_cvt_pkrtz(F1f[2],F1f[3]);
      F1p[jj][2]=__builtin_amdgcn_cvt_pkrtz(F1f[4],F1f[5]);
      F1p[jj][3]=__builtin_amdgcn_cvt_pkrtz(F1f[6],F1f[7]);
    }
    h2 Wvp = __builtin_amdgcn_cvt_pkrtz(Wv[0], Wv[1]);

    const u32* kArow = &K16[jA*32];
    const u32* kBrow = &K16[jB*32];
    const u32* vrow  = &V16[(((u32)jbase>>1)+jl)*64];

    #pragma unroll
    for (int h=0;h<8;h++) {
      uint4 qh = *(const uint4*)&sQ16[r*36 + (h<<2)];
      uint4 kA = *(const uint4*)&kArow[h<<2];
      uint4 kB = *(const uint4*)&kBrow[h<<2];
      float S0 = dot2(u2h(qh.x),u2h(kA.x), dot2(u2h(qh.y),u2h(kA.y), 0.f))
               + dot2(u2h(qh.z),u2h(kA.z), dot2(u2h(qh.w),u2h(kA.w), 0.f));
      float S1 = dot2(u2h(qh.x),u2h(kB.x), dot2(u2h(qh.y),u2h(kB.y), 0.f))
               + dot2(u2h(qh.z),u2h(kB.z), dot2(u2h(qh.w),u2h(kB.w), 0.f));
      float e0 = __builtin_amdgcn_exp2f(S0);
      float e1 = __builtin_amdgcn_exp2f(S1);
      lh[h] += e0 + e1;
      h2 ewp = __builtin_amdgcn_cvt_pkrtz(e0,e1) * Wvp;
      uint4 vpA = *(const uint4*)&vrow[h*8];
      uint4 vpB = *(const uint4*)&vrow[h*8+4];
      u32 vparr[8] = {vpA.x,vpA.y,vpA.z,vpA.w,vpB.x,vpB.y,vpB.z,vpB.w};
      #pragma unroll
      for (int cc=0;cc<8;cc++){
        int rw = h*8+cc;
        h2 w0=u2h(w2p[rw*4+0]), w1h=u2h(w2p[rw*4+1]), w2h=u2h(w2p[rw*4+2]), w3h=u2h(w2p[rw*4+3]);
        float b2v = b2g[rw];
        float fh0 = dot2(F1p[0][0],w0, dot2(F1p[0][1],w1h, b2v))
                  + dot2(F1p[0][2],w2h, dot2(F1p[0][3],w3h, 0.f));
        float fh1 = dot2(F1p[1][0],w0, dot2(F1p[1][1],w1h, b2v))
                  + dot2(F1p[1][2],w2h, dot2(F1p[1][3],w3h, 0.f));
        h2 fhp = __builtin_amdgcn_cvt_pkrtz(fmaxf(fh0,0.f), fmaxf(fh1,0.f));
        h2 ev = u2h(vparr[cc]) * ewp;
        acc[rw] = dot2(fhp, ev, acc[rw]);
      }
    }
  }

  // reduce over 4 jl-lanes within wave (lanes r, r+16, r+32, r+48)
  #pragma unroll
  for (int o=0;o<64;o++){ acc[o] += __shfl_xor(acc[o],16); acc[o] += __shfl_xor(acc[o],32); }
  #pragma unroll
  for (int h=0;h<8;h++){ lh[h] += __shfl_xor(lh[h],16); lh[h] += __shfl_xor(lh[h],32); }
  __syncthreads();   // sQ16/sWX reads done; sRed alias safe
  int wv = t >> 6, lane = t & 63;
  if (lane < 16) {
    #pragma unroll
    for (int o=0;o<64;o++) sRed[(wv*16+lane)*72+o] = acc[o];
    #pragma unroll
    for (int h=0;h<8;h++) sRed[(wv*16+lane)*72+64+h] = lh[h];
  }
  __syncthreads();
  for (int v2 = t; v2 < 16*72; v2 += 512) {
    int rr = v2/72, o = v2 - rr*72;
    float s = 0.f;
    #pragma unroll
    for (int q=0;q<8;q++) s += sRed[(q*16+rr)*72+o];
    part[(jc*NPTS + I0 + rr)*72 + o] = s;
  }
}

// ---------------- K4: merge chunk partials, divide, output MLP, out-stat partials ----------------
__global__ __launch_bounds__(256) void k_agg(
  const float* __restrict__ part, const float* __restrict__ w_o1, const float* __restrict__ b_o1,
  const float* __restrict__ w_o2, const float* __restrict__ b_o2,
  float* __restrict__ o2b, float* __restrict__ bstat2)
{
  __shared__ float sh[4][64];
  __shared__ float sred[4][8];
  int t = threadIdx.x, w = t>>6, c = t&63;
  int i = blockIdx.x*4 + w;
  int h = c>>3;
  float a = 0.f, L = 0.f;
  #pragma unroll
  for (int jc=0;jc<NCHUNK;jc++){
    const float* p = part + (jc*NPTS + i)*72;
    a += p[c]; L += p[64+h];
  }
  float agg = a / L;
  sh[w][c] = agg; __syncthreads();
  float o1 = b_o1[c];
  #pragma unroll
  for (int k4=0;k4<16;k4++){
    float4 hv = *(const float4*)&sh[w][k4*4];
    o1 += d4(hv, *(const float4*)&w_o1[c*64+k4*4]);
  }
  o1 = leaky(o1);
  __syncthreads();
  sh[w][c] = o1; __syncthreads();
  float o2 = b_o2[c];
  #pragma unroll
  for (int k4=0;k4<16;k4++){
    float4 hv = *(const float4*)&sh[w][k4*4];
    o2 += d4(hv, *(const float4*)&w_o2[c*64+k4*4]);
  }
  o2 = leaky(o2);
  o2b[i*64+c] = o2;

  float s = o2, qq = o2*o2;
  s += __shfl_xor(s,1);  qq += __shfl_xor(qq,1);
  s += __shfl_xor(s,2);  qq += __shfl_xor(qq,2);
  s += __shfl_xor(s,4);  qq += __shfl_xor(qq,4);
  s += __shfl_xor(s,8);  qq += __shfl_xor(qq,8);
  if ((c&15)==0){ int g=c>>4; sred[w][g]=s; sred[w][4+g]=qq; }
  __syncthreads();
  if (t<8) bstat2[blockIdx.x*8+t] = sred[0][t]+sred[1][t]+sred[2][t]+sred[3][t];
}

// ---------------- K5: reduce out-stats, final group-norm + residual ----------------
__global__ __launch_bounds__(256) void k_out(
  const float* __restrict__ o2b, const float* __restrict__ bstat2,
  const float* __restrict__ g_out, const float* __restrict__ be_out,
  const float* __restrict__ feat, const float* __restrict__ w_res, const float* __restrict__ b_res,
  float* __restrict__ out)
{
  __shared__ float sp[64];
  __shared__ float sst[8];
  int t = threadIdx.x, w = t>>6, c = t&63;
  int i = blockIdx.x*4 + w;
  if (t<64){ int g=t&7; float s=0.f;
    for (int m=t>>3; m<400; m+=8) s += bstat2[m*8+g];
    sp[t]=s; }
  __syncthreads();
  if (t<8){ float s=0.f;
    #pragma unroll
    for (int q=0;q<8;q++) s += sp[q*8+t];
    sst[t]=s; }
  __syncthreads();
  int g = c>>4;
  const float inv = 1.f/25600.f;
  float mu = sst[g]*inv;
  float var = sst[4+g]*inv - mu*mu;
  float rs = rsqrtf(var + 1e-5f);
  float on = (o2b[i*64+c]-mu)*rs*g_out[c] + be_out[c];
  const float4* f4 = (const float4*)(feat + i*16);
  const float4* wr = (const float4*)(w_res + c*16);
  float res = b_res[c] + d4(f4[0],wr[0]) + d4(f4[1],wr[1]) + d4(f4[2],wr[2]) + d4(f4[3],wr[3]);
  out[i*64+c] = on + res;
}

extern "C" void kernel_launch(void* const* d_in, const int* in_sizes, int n_in,
                              void* d_out, int out_size, void* d_ws, size_t ws_size,
                              hipStream_t stream) {
  const float* points  = (const float*)d_in[0];
  const float* nuv     = (const float*)d_in[1];
  const float* feat    = (const float*)d_in[2];
  const float* w_in1   = (const float*)d_in[3];
  const float* b_in1   = (const float*)d_in[4];
  const float* w_in2   = (const float*)d_in[5];
  const float* b_in2   = (const float*)d_in[6];
  const float* g_in    = (const float*)d_in[7];
  const float* be_in   = (const float*)d_in[8];
  const float* wq      = (const float*)d_in[9];
  const float* bq      = (const float*)d_in[10];
  const float* wk      = (const float*)d_in[11];
  const float* bk      = (const float*)d_in[12];
  const float* wv      = (const float*)d_in[13];
  const float* bv      = (const float*)d_in[14];
  const float* conv_w1 = (const float*)d_in[15];
  const float* conv_b1 = (const float*)d_in[16];
  const float* conv_w2 = (const float*)d_in[17];
  const float* conv_b2 = (const float*)d_in[18];
  const float* rbf_ls  = (const float*)d_in[19];
  const float* rbf_a   = (const float*)d_in[20];
  const float* rbf_b   = (const float*)d_in[21];
  const float* rbf_c   = (const float*)d_in[22];
  const float* w_o1    = (const float*)d_in[23];
  const float* b_o1    = (const float*)d_in[24];
  const float* w_o2    = (const float*)d_in[25];
  const float* b_o2    = (const float*)d_in[26];
  const float* g_out   = (const float*)d_in[27];
  const float* be_out  = (const float*)d_in[28];
  const float* w_res   = (const float*)d_in[29];
  const float* b_res   = (const float*)d_in[30];

  float* ws     = (float*)d_ws;
  float* h2f    = ws;                 // 102400
  u32*   Q16    = (u32*)(ws + 102400);// 51200 u32
  u32*   K16    = (u32*)(ws + 153600);// 51200 u32
  u32*   V16    = (u32*)(ws + 204800);// 51200 u32
  float* PN     = ws + 256000;        // 12800
  float* bstat1 = ws + 268800;        // 3200
  float* bstat2 = ws + 272000;        // 3200
  float* wpk    = ws + 275200;        // 320
  float* part   = ws + 275520;        // 5*1600*72 = 576000
  float* o2b    = ws + 851520;        // 102400
  float* out    = (float*)d_out;

  k_in<<<400, 256, 0, stream>>>(feat, w_in1, b_in1, w_in2, b_in2,
                                conv_w1, conv_b1, conv_w2, rbf_a, rbf_b, rbf_ls, rbf_c,
                                h2f, bstat1, wpk);
  k_qkv<<<400, 256, 0, stream>>>(h2f, bstat1, g_in, be_in, wq, bq, wk, bk, wv, bv,
                                 points, nuv, Q16, K16, V16, PN);
  k_pair<<<500, 512, 0, stream>>>(Q16, K16, V16, PN, nuv, conv_w1, wpk, conv_b2, part);
  k_agg<<<400, 256, 0, stream>>>(part, w_o1, b_o1, w_o2, b_o2, o2b, bstat2);
  k_out<<<400, 256, 0, stream>>>(o2b, bstat2, g_out, be_out, feat, w_res, b_res, out);
}

// Round 11
// 252.376 us; speedup vs baseline: 1.0415x; 1.0234x over previous
//
#include <hip/hip_runtime.h>

typedef __fp16 h2 __attribute__((ext_vector_type(2)));
typedef unsigned int u32;
typedef unsigned short u16;

#define NPTS 1600
#define NCHUNK 10
#define CHUNKJ 160
#define TILE 32
// softmax scale * log2e folded into Q
#define QS (0.35355339059327373f*1.4426950408889634f)
// 1/(sqrt(2)*6)
#define PSCALE 0.11785113019775793f
#define LOG2E 1.4426950408889634f

__device__ __forceinline__ float leaky(float x){ return x >= 0.f ? x : 0.2f*x; }
__device__ __forceinline__ float d4(float4 a, float4 b){ return a.x*b.x + a.y*b.y + a.z*b.z + a.w*b.w; }
__device__ __forceinline__ u32 pkn(float a, float b){ h2 v; v[0]=(__fp16)a; v[1]=(__fp16)b; return __builtin_bit_cast(u32,v); }
__device__ __forceinline__ h2 u2h(u32 u){ return __builtin_bit_cast(h2,u); }
__device__ __forceinline__ float dot2(h2 a, h2 b, float c){ return __builtin_amdgcn_fdot2(a,b,c,false); }
__device__ __forceinline__ u32 rfl(u32 x){ return (u32)__builtin_amdgcn_readfirstlane((int)x); }

// ---------------- K1: input MLP + group stats partials + weight packing ----------------
__global__ __launch_bounds__(256) void k_in(
    const float* __restrict__ feat, const float* __restrict__ w1, const float* __restrict__ b1,
    const float* __restrict__ w2, const float* __restrict__ b2,
    const float* __restrict__ conv_w1, const float* __restrict__ conv_b1,
    const float* __restrict__ conv_w2,
    const float* __restrict__ rbf_a, const float* __restrict__ rbf_b,
    const float* __restrict__ rbf_ls, const float* __restrict__ rbf_c,
    float* __restrict__ h2out, float* __restrict__ bstat1, float* __restrict__ wpk)
{
  __shared__ float sh[4][64];
  __shared__ float sred[4][8];
  int t = threadIdx.x, w = t>>6, c = t&63;
  int i = blockIdx.x*4 + w;

  if (blockIdx.x == 0) {
    u32* wp = (u32*)wpk;
    { // w2 packed f16: 64 rows x 4 u32
      int row = t>>2, q = t&3;
      wp[32 + row*4 + q] = pkn(conv_w2[row*8+2*q], conv_w2[row*8+2*q+1]);
    }
    if (t < 32) { // folded rbf weights: wrg = conv_w1[:,4:8] @ rbf_a
      int cc = t>>2, kq = t&3;
      float a0=0.f, a1=0.f;
      #pragma unroll
      for (int p=0;p<4;p++){ a0 += conv_w1[cc*8+4+p]*rbf_a[p*8+2*kq]; a1 += conv_w1[cc*8+4+p]*rbf_a[p*8+2*kq+1]; }
      wp[cc*4+kq] = pkn(a0,a1);
    } else if (t < 40) { // b1' = conv_b1 + conv_w1[:,4:8] @ rbf_b
      int cc = t-32; float s = conv_b1[cc];
      #pragma unroll
      for (int p=0;p<4;p++) s += conv_w1[cc*8+4+p]*rbf_b[p];
      wpk[288+cc] = s;
    } else if (t == 40) { // rbf coefficients: R[k]=E*U^k*A^(k^2), A const
      float sig = fmaxf(expf(rbf_ls[0]), 1e-6f);
      float m = -LOG2E/(2.f*sig*sig);
      float c0 = rbf_c[0];
      float dl = rbf_c[1] - rbf_c[0];
      float A1v = m*dl*dl;
      wpk[296] = c0;
      wpk[297] = m;
      wpk[298] = -2.f*m*dl;        // C2 (per-pair: U = exp2(C2*g0))
      wpk[299] = A1v;
      float Av = exp2f(A1v);
      wpk[300] = Av;               // A
      wpk[301] = Av*Av;            // A^2
    }
  }

  const float4* f4 = (const float4*)(feat + i*16);
  float4 f0=f4[0], f1v=f4[1], f2v=f4[2], f3v=f4[3];
  const float4* w1r = (const float4*)(w1 + c*16);
  float h1 = b1[c] + d4(f0,w1r[0]) + d4(f1v,w1r[1]) + d4(f2v,w1r[2]) + d4(f3v,w1r[3]);
  h1 = leaky(h1);
  sh[w][c] = h1;
  __syncthreads();
  float hh = b2[c];
  #pragma unroll
  for (int k4=0;k4<16;k4++){
    float4 hv = *(const float4*)&sh[w][k4*4];
    hh += d4(hv, *(const float4*)&w2[c*64 + k4*4]);
  }
  hh = leaky(hh);
  h2out[i*64+c] = hh;

  float s = hh, qq = hh*hh;
  s += __shfl_xor(s,1);  qq += __shfl_xor(qq,1);
  s += __shfl_xor(s,2);  qq += __shfl_xor(qq,2);
  s += __shfl_xor(s,4);  qq += __shfl_xor(qq,4);
  s += __shfl_xor(s,8);  qq += __shfl_xor(qq,8);
  if ((c&15)==0){ int g=c>>4; sred[w][g]=s; sred[w][4+g]=qq; }
  __syncthreads();
  if (t<8) bstat1[blockIdx.x*8+t] = sred[0][t]+sred[1][t]+sred[2][t]+sred[3][t];
}

// ---------------- K2: reduce stats, group-norm, packed Q/K/V + PN ----------------
__global__ __launch_bounds__(256) void k_qkv(
  const float* __restrict__ h2b, const float* __restrict__ bstat1,
  const float* __restrict__ g_in, const float* __restrict__ be_in,
  const float* __restrict__ wq, const float* __restrict__ bq,
  const float* __restrict__ wk, const float* __restrict__ bk,
  const float* __restrict__ wv, const float* __restrict__ bv,
  const float* __restrict__ pts, const float* __restrict__ nuv,
  u32* __restrict__ Q16, u32* __restrict__ K16, u32* __restrict__ V16,
  float* __restrict__ PN)
{
  __shared__ float sh[4][64];
  __shared__ float sp[64];
  __shared__ float sst[8];
  int t=threadIdx.x, w=t>>6, c=t&63;
  int i = blockIdx.x*4 + w;
  if (t<64){ int g=t&7; float s=0.f;
    for (int m=t>>3; m<400; m+=8) s += bstat1[m*8+g];
    sp[t]=s; }
  __syncthreads();
  if (t<8){ float s=0.f;
    #pragma unroll
    for (int q=0;q<8;q++) s += sp[q*8+t];
    sst[t]=s; }
  __syncthreads();
  int g = c>>4;
  const float inv = 1.f/25600.f;
  float mu = sst[g]*inv;
  float var = sst[4+g]*inv - mu*mu;
  float rs = rsqrtf(var + 1e-5f);
  float hn = (h2b[i*64+c]-mu)*rs*g_in[c] + be_in[c];
  sh[w][c] = hn;
  __syncthreads();
  float q=bq[c], k=bk[c], v=bv[c];
  #pragma unroll
  for (int k4=0;k4<16;k4++){
    float4 hv = *(const float4*)&sh[w][k4*4];
    q += d4(hv, *(const float4*)&wq[c*64+k4*4]);
    k += d4(hv, *(const float4*)&wk[c*64+k4*4]);
    v += d4(hv, *(const float4*)&wv[c*64+k4*4]);
  }
  // packed outputs
  u16* Q16u = (u16*)Q16;
  u16* K16u = (u16*)K16;
  u16* V16u = (u16*)V16;
  __fp16 qh = (__fp16)(q*QS);
  __fp16 kh = (__fp16)k;
  __fp16 vh = (__fp16)v;
  Q16u[i*64 + c] = __builtin_bit_cast(u16, qh);
  K16u[i*64 + c] = __builtin_bit_cast(u16, kh);
  int pr = ((i>>5)<<4) + (i&15);   // pair row: (j, j+16) within 32-group
  int hf = (i>>4)&1;
  V16u[(pr*64 + c)*2 + hf] = __builtin_bit_cast(u16, vh);
  if (c < 6){
    float pv = (c<3) ? pts[i*3+c]*PSCALE : nuv[i*9+(c-3)];
    PN[i*8+c] = pv;
  } else if (c < 8) PN[i*8+c] = 0.f;
}

// ---------------- K3: all-pairs kernel — R7 shape + RBF recurrence + split chains ----------------
__global__ __launch_bounds__(256) void k_pair(
  const u32* __restrict__ Q16, const u32* __restrict__ K16, const u32* __restrict__ V16,
  const float* __restrict__ PN, const float* __restrict__ nuv,
  const float* __restrict__ w1, const float* __restrict__ wpk,
  const float* __restrict__ b2g, float* __restrict__ part)
{
  __shared__ __align__(16) float SM[4608];
  u32* sQ16 = (u32*)SM;            // [16][36]
  u32* sWX  = (u32*)SM + 576;      // [16][20]
  float* sRed = SM;                // [4][16][72] alias (post-loop only, behind barrier)

  int t = threadIdx.x;
  int r = t & 15, jl = t >> 4;
  int bx = blockIdx.x;
  int rb = bx % 100, jc = bx / 100;
  int I0 = rb*16, J0 = jc*CHUNKJ;
  int i = I0 + r;

  if (t < 128) { // stage Q16 tile: 16x32 u32
    int qrow = t>>3, qq4 = (t&7)<<2;
    *(uint4*)&sQ16[qrow*36+qq4] = *(const uint4*)&Q16[(I0+qrow)*32+qq4];
  }
  if (t < 128) { // wx[c][:] = conv_w1[c,0:3] @ nuv[i] ; last = conv_w1[c,3]
    int r2 = t>>3, cc = t&7, ib = (I0+r2)*9;
    float a0=w1[cc*8], a1=w1[cc*8+1], a2=w1[cc*8+2];
    float x = a0*nuv[ib+0] + a1*nuv[ib+3] + a2*nuv[ib+6];
    float y = a0*nuv[ib+1] + a1*nuv[ib+4] + a2*nuv[ib+7];
    float z = a0*nuv[ib+2] + a1*nuv[ib+5] + a2*nuv[ib+8];
    sWX[r2*20+cc*2+0] = pkn(x,y);
    sWX[r2*20+cc*2+1] = pkn(z, w1[cc*8+3]);
  }
  __syncthreads();

  const u32* wp = (const u32*)wpk;
  h2 wr[8][4];   // wave-uniform
  #pragma unroll
  for (int cc=0;cc<8;cc++)
    #pragma unroll
    for (int q2=0;q2<4;q2++) wr[cc][q2] = u2h(rfl(wp[cc*4+q2]));
  const u32* w2p = wp + 32;
  const float* b1p = wpk + 288;
  float c0  = wpk[296];
  float mco = wpk[297];
  float C2  = wpk[298];
  float Af  = wpk[300];
  float A2f = wpk[301];

  float4 pni0 = *(const float4*)&PN[i*8];
  float4 pni1 = *(const float4*)&PN[i*8+4];
  float pix = pni0.x, piy = pni0.y, piz = pni0.z;
  float nix = pni0.w, niy = pni1.x, niz = pni1.y;

  float acc[64];
  #pragma unroll
  for (int o=0;o<64;o++) acc[o] = 0.f;
  float lh[8];
  #pragma unroll
  for (int h=0;h<8;h++) lh[h] = 0.f;

  #pragma unroll 1
  for (int tb=0; tb<CHUNKJ; tb+=TILE) {
    int jbase = J0 + tb;
    int jA = jbase + jl;
    int jB = jA + 16;

    h2 F1p[2][4];
    float Wv[2];
    #pragma unroll
    for (int jj=0;jj<2;jj++) {
      int j = jj ? jB : jA;
      float4 a0 = *(const float4*)&PN[j*8];
      float4 a1 = *(const float4*)&PN[j*8+4];
      float dx = a0.x-pix, dy = a0.y-piy, dz = a0.z-piz;
      float ndot = nix*a0.w + niy*a1.x + niz*a1.y;
      float d2r = dx*dx + dy*dy + dz*dz;
      float wf = 2.f - ndot;
      float d2 = d2r*wf*wf;
      float tp = fmaf(d2, 0.3333333333333333f, 1.f);
      Wv[jj] = __builtin_amdgcn_rcpf(tp*tp*tp);     // (1+d2/3)^-3
      float dd = __builtin_amdgcn_sqrtf(d2);
      float g0 = dd - c0;
      float E = __builtin_amdgcn_exp2f(mco*g0*g0);
      float U = __builtin_amdgcn_exp2f(C2*g0);
      float R[8];
      R[0] = E;
      float tt = U*Af;
      #pragma unroll
      for (int k=1;k<8;k++){ R[k] = R[k-1]*tt; tt *= A2f; }
      h2 xv0; xv0[0]=(__fp16)dx; xv0[1]=(__fp16)dy;
      h2 xv1; xv1[0]=(__fp16)dz; xv1[1]=(__fp16)ndot;
      h2 r01=__builtin_amdgcn_cvt_pkrtz(R[0],R[1]);
      h2 r23=__builtin_amdgcn_cvt_pkrtz(R[2],R[3]);
      h2 r45=__builtin_amdgcn_cvt_pkrtz(R[4],R[5]);
      h2 r67=__builtin_amdgcn_cvt_pkrtz(R[6],R[7]);
      float F1f[8];
      #pragma unroll
      for (int cc=0;cc<8;cc++){
        uint2 wx2 = *(const uint2*)&sWX[r*20+cc*2];
        float fa = dot2(r01, wr[cc][0], dot2(r23, wr[cc][1], b1p[cc]));
        float fb = dot2(r45, wr[cc][2], dot2(r67, wr[cc][3], 0.f));
        float fc = dot2(u2h(wx2.x), xv0, dot2(u2h(wx2.y), xv1, 0.f));
        F1f[cc] = fmaxf(fa+fb+fc, 0.f);
      }
      F1p[jj][0]=__builtin_amdgcn_cvt_pkrtz(F1f[0],F1f[1]);
      F1p[jj][1]=__builtin_amdgcn_cvt_pkrtz(F1f[2],F1f[3]);
      F1p[jj][2]=__builtin_amdgcn_cvt_pkrtz(F1f[4],F1f[5]);
      F1p[jj][3]=__builtin_amdgcn_cvt_pkrtz(F1f[6],F1f[7]);
    }
    h2 Wvp = __builtin_amdgcn_cvt_pkrtz(Wv[0], Wv[1]);

    const u32* kArow = &K16[jA*32];
    const u32* kBrow = &K16[jB*32];
    const u32* vrow  = &V16[(((u32)jbase>>1)+jl)*64];

    #pragma unroll
    for (int h=0;h<8;h++) {
      uint4 qh = *(const uint4*)&sQ16[r*36 + (h<<2)];
      uint4 kA = *(const uint4*)&kArow[h<<2];
      uint4 kB = *(const uint4*)&kBrow[h<<2];
      float S0 = dot2(u2h(qh.x),u2h(kA.x), dot2(u2h(qh.y),u2h(kA.y), 0.f))
               + dot2(u2h(qh.z),u2h(kA.z), dot2(u2h(qh.w),u2h(kA.w), 0.f));
      float S1 = dot2(u2h(qh.x),u2h(kB.x), dot2(u2h(qh.y),u2h(kB.y), 0.f))
               + dot2(u2h(qh.z),u2h(kB.z), dot2(u2h(qh.w),u2h(kB.w), 0.f));
      float e0 = __builtin_amdgcn_exp2f(S0);
      float e1 = __builtin_amdgcn_exp2f(S1);
      lh[h] += e0 + e1;
      h2 ewp = __builtin_amdgcn_cvt_pkrtz(e0,e1) * Wvp;
      uint4 vpA = *(const uint4*)&vrow[h*8];
      uint4 vpB = *(const uint4*)&vrow[h*8+4];
      #pragma unroll
      for (int cc=0;cc<8;cc++){
        int rw = h*8+cc;
        h2 w0=u2h(w2p[rw*4+0]), w1h=u2h(w2p[rw*4+1]), w2h=u2h(w2p[rw*4+2]), w3h=u2h(w2p[rw*4+3]);
        float b2v = b2g[rw];
        float fh0 = dot2(F1p[0][0],w0, dot2(F1p[0][1],w1h, b2v))
                  + dot2(F1p[0][2],w2h, dot2(F1p[0][3],w3h, 0.f));
        float fh1 = dot2(F1p[1][0],w0, dot2(F1p[1][1],w1h, b2v))
                  + dot2(F1p[1][2],w2h, dot2(F1p[1][3],w3h, 0.f));
        h2 fhp = __builtin_amdgcn_cvt_pkrtz(fmaxf(fh0,0.f), fmaxf(fh1,0.f));
        u32 vp = (cc<4) ? ((cc==0)?vpA.x:(cc==1)?vpA.y:(cc==2)?vpA.z:vpA.w)
                        : ((cc==4)?vpB.x:(cc==5)?vpB.y:(cc==6)?vpB.z:vpB.w);
        h2 ev = u2h(vp) * ewp;
        acc[rw] = dot2(fhp, ev, acc[rw]);
      }
    }
  }

  #pragma unroll
  for (int o=0;o<64;o++){ acc[o] += __shfl_xor(acc[o],16); acc[o] += __shfl_xor(acc[o],32); }
  #pragma unroll
  for (int h=0;h<8;h++){ lh[h] += __shfl_xor(lh[h],16); lh[h] += __shfl_xor(lh[h],32); }
  __syncthreads();   // sQ16/sWX reads done; sRed alias safe
  int wv = t >> 6, lane = t & 63;
  if (lane < 16) {
    #pragma unroll
    for (int o=0;o<64;o++) sRed[(wv*16+lane)*72+o] = acc[o];
    #pragma unroll
    for (int h=0;h<8;h++) sRed[(wv*16+lane)*72+64+h] = lh[h];
  }
  __syncthreads();
  for (int v2 = t; v2 < 16*72; v2 += 256) {
    int rr = v2/72, o = v2 - rr*72;
    part[(jc*NPTS + I0 + rr)*72 + o] =
      sRed[(0*16+rr)*72+o] + sRed[(1*16+rr)*72+o] + sRed[(2*16+rr)*72+o] + sRed[(3*16+rr)*72+o];
  }
}

// ---------------- K4: merge chunk partials, divide, output MLP, out-stat partials ----------------
__global__ __launch_bounds__(256) void k_agg(
  const float* __restrict__ part, const float* __restrict__ w_o1, const float* __restrict__ b_o1,
  const float* __restrict__ w_o2, const float* __restrict__ b_o2,
  float* __restrict__ o2b, float* __restrict__ bstat2)
{
  __shared__ float sh[4][64];
  __shared__ float sred[4][8];
  int t = threadIdx.x, w = t>>6, c = t&63;
  int i = blockIdx.x*4 + w;
  int h = c>>3;
  float a = 0.f, L = 0.f;
  #pragma unroll
  for (int jc=0;jc<NCHUNK;jc++){
    const float* p = part + (jc*NPTS + i)*72;
    a += p[c]; L += p[64+h];
  }
  float agg = a / L;
  sh[w][c] = agg; __syncthreads();
  float o1 = b_o1[c];
  #pragma unroll
  for (int k4=0;k4<16;k4++){
    float4 hv = *(const float4*)&sh[w][k4*4];
    o1 += d4(hv, *(const float4*)&w_o1[c*64+k4*4]);
  }
  o1 = leaky(o1);
  __syncthreads();
  sh[w][c] = o1; __syncthreads();
  float o2 = b_o2[c];
  #pragma unroll
  for (int k4=0;k4<16;k4++){
    float4 hv = *(const float4*)&sh[w][k4*4];
    o2 += d4(hv, *(const float4*)&w_o2[c*64+k4*4]);
  }
  o2 = leaky(o2);
  o2b[i*64+c] = o2;

  float s = o2, qq = o2*o2;
  s += __shfl_xor(s,1);  qq += __shfl_xor(qq,1);
  s += __shfl_xor(s,2);  qq += __shfl_xor(qq,2);
  s += __shfl_xor(s,4);  qq += __shfl_xor(qq,4);
  s += __shfl_xor(s,8);  qq += __shfl_xor(qq,8);
  if ((c&15)==0){ int g=c>>4; sred[w][g]=s; sred[w][4+g]=qq; }
  __syncthreads();
  if (t<8) bstat2[blockIdx.x*8+t] = sred[0][t]+sred[1][t]+sred[2][t]+sred[3][t];
}

// ---------------- K5: reduce out-stats, final group-norm + residual ----------------
__global__ __launch_bounds__(256) void k_out(
  const float* __restrict__ o2b, const float* __restrict__ bstat2,
  const float* __restrict__ g_out, const float* __restrict__ be_out,
  const float* __restrict__ feat, const float* __restrict__ w_res, const float* __restrict__ b_res,
  float* __restrict__ out)
{
  __shared__ float sp[64];
  __shared__ float sst[8];
  int t = threadIdx.x, w = t>>6, c = t&63;
  int i = blockIdx.x*4 + w;
  if (t<64){ int g=t&7; float s=0.f;
    for (int m=t>>3; m<400; m+=8) s += bstat2[m*8+g];
    sp[t]=s; }
  __syncthreads();
  if (t<8){ float s=0.f;
    #pragma unroll
    for (int q=0;q<8;q++) s += sp[q*8+t];
    sst[t]=s; }
  __syncthreads();
  int g = c>>4;
  const float inv = 1.f/25600.f;
  float mu = sst[g]*inv;
  float var = sst[4+g]*inv - mu*mu;
  float rs = rsqrtf(var + 1e-5f);
  float on = (o2b[i*64+c]-mu)*rs*g_out[c] + be_out[c];
  const float4* f4 = (const float4*)(feat + i*16);
  const float4* wr = (const float4*)(w_res + c*16);
  float res = b_res[c] + d4(f4[0],wr[0]) + d4(f4[1],wr[1]) + d4(f4[2],wr[2]) + d4(f4[3],wr[3]);
  out[i*64+c] = on + res;
}

extern "C" void kernel_launch(void* const* d_in, const int* in_sizes, int n_in,
                              void* d_out, int out_size, void* d_ws, size_t ws_size,
                              hipStream_t stream) {
  const float* points  = (const float*)d_in[0];
  const float* nuv     = (const float*)d_in[1];
  const float* feat    = (const float*)d_in[2];
  const float* w_in1   = (const float*)d_in[3];
  const float* b_in1   = (const float*)d_in[4];
  const float* w_in2   = (const float*)d_in[5];
  const float* b_in2   = (const float*)d_in[6];
  const float* g_in    = (const float*)d_in[7];
  const float* be_in   = (const float*)d_in[8];
  const float* wq      = (const float*)d_in[9];
  const float* bq      = (const float*)d_in[10];
  const float* wk      = (const float*)d_in[11];
  const float* bk      = (const float*)d_in[12];
  const float* wv      = (const float*)d_in[13];
  const float* bv      = (const float*)d_in[14];
  const float* conv_w1 = (const float*)d_in[15];
  const float* conv_b1 = (const float*)d_in[16];
  const float* conv_w2 = (const float*)d_in[17];
  const float* conv_b2 = (const float*)d_in[18];
  const float* rbf_ls  = (const float*)d_in[19];
  const float* rbf_a   = (const float*)d_in[20];
  const float* rbf_b   = (const float*)d_in[21];
  const float* rbf_c   = (const float*)d_in[22];
  const float* w_o1    = (const float*)d_in[23];
  const float* b_o1    = (const float*)d_in[24];
  const float* w_o2    = (const float*)d_in[25];
  const float* b_o2    = (const float*)d_in[26];
  const float* g_out   = (const float*)d_in[27];
  const float* be_out  = (const float*)d_in[28];
  const float* w_res   = (const float*)d_in[29];
  const float* b_res   = (const float*)d_in[30];

  float* ws     = (float*)d_ws;
  float* h2f    = ws;                 // 102400
  u32*   Q16    = (u32*)(ws + 102400);// 51200 u32
  u32*   K16    = (u32*)(ws + 153600);// 51200 u32
  u32*   V16    = (u32*)(ws + 204800);// 51200 u32
  float* PN     = ws + 256000;        // 12800
  float* bstat1 = ws + 268800;        // 3200
  float* bstat2 = ws + 272000;        // 3200
  float* wpk    = ws + 275200;        // 320
  float* part   = ws + 275520;        // 10*1600*72 = 1152000
  float* o2b    = ws + 1427520;       // 102400
  float* out    = (float*)d_out;

  k_in<<<400, 256, 0, stream>>>(feat, w_in1, b_in1, w_in2, b_in2,
                                conv_w1, conv_b1, conv_w2, rbf_a, rbf_b, rbf_ls, rbf_c,
                                h2f, bstat1, wpk);
  k_qkv<<<400, 256, 0, stream>>>(h2f, bstat1, g_in, be_in, wq, bq, wk, bk, wv, bv,
                                 points, nuv, Q16, K16, V16, PN);
  k_pair<<<1000, 256, 0, stream>>>(Q16, K16, V16, PN, nuv, conv_w1, wpk, conv_b2, part);
  k_agg<<<400, 256, 0, stream>>>(part, w_o1, b_o1, w_o2, b_o2, o2b, bstat2);
  k_out<<<400, 256, 0, stream>>>(o2b, bstat2, g_out, be_out, feat, w_res, b_res, out);
}

// Round 13
// 238.505 us; speedup vs baseline: 1.1021x; 1.0582x over previous
//
#include <hip/hip_runtime.h>

typedef __fp16 h2 __attribute__((ext_vector_type(2)));
typedef unsigned int u32;
typedef unsigned short u16;

#define NPTS 1600
#define NCHUNK 10
#define CHUNKJ 160
#define TILE 32
// softmax scale * log2e folded into Q
#define QS (0.35355339059327373f*1.4426950408889634f)
// 1/(sqrt(2)*6)
#define PSCALE 0.11785113019775793f
#define LOG2E 1.4426950408889634f

__device__ __forceinline__ float leaky(float x){ return x >= 0.f ? x : 0.2f*x; }
__device__ __forceinline__ float d4(float4 a, float4 b){ return a.x*b.x + a.y*b.y + a.z*b.z + a.w*b.w; }
__device__ __forceinline__ u32 pkn(float a, float b){ h2 v; v[0]=(__fp16)a; v[1]=(__fp16)b; return __builtin_bit_cast(u32,v); }
__device__ __forceinline__ h2 u2h(u32 u){ return __builtin_bit_cast(h2,u); }
__device__ __forceinline__ float dot2(h2 a, h2 b, float c){ return __builtin_amdgcn_fdot2(a,b,c,false); }
__device__ __forceinline__ u32 rfl(u32 x){ return (u32)__builtin_amdgcn_readfirstlane((int)x); }

// ---------------- K1: input MLP + group stats partials + weight packing ----------------
__global__ __launch_bounds__(256) void k_in(
    const float* __restrict__ feat, const float* __restrict__ w1, const float* __restrict__ b1,
    const float* __restrict__ w2, const float* __restrict__ b2,
    const float* __restrict__ conv_w1, const float* __restrict__ conv_b1,
    const float* __restrict__ conv_w2,
    const float* __restrict__ rbf_a, const float* __restrict__ rbf_b,
    const float* __restrict__ rbf_ls, const float* __restrict__ rbf_c,
    float* __restrict__ h2out, float* __restrict__ bstat1, float* __restrict__ wpk)
{
  __shared__ float sh[4][64];
  __shared__ float sred[4][8];
  int t = threadIdx.x, w = t>>6, c = t&63;
  int i = blockIdx.x*4 + w;

  if (blockIdx.x == 0) {
    u32* wp = (u32*)wpk;
    { // w2 packed f16: 64 rows x 4 u32
      int row = t>>2, q = t&3;
      wp[32 + row*4 + q] = pkn(conv_w2[row*8+2*q], conv_w2[row*8+2*q+1]);
    }
    if (t < 32) { // folded rbf weights: wrg = conv_w1[:,4:8] @ rbf_a
      int cc = t>>2, kq = t&3;
      float a0=0.f, a1=0.f;
      #pragma unroll
      for (int p=0;p<4;p++){ a0 += conv_w1[cc*8+4+p]*rbf_a[p*8+2*kq]; a1 += conv_w1[cc*8+4+p]*rbf_a[p*8+2*kq+1]; }
      wp[cc*4+kq] = pkn(a0,a1);
    } else if (t < 40) { // b1' = conv_b1 + conv_w1[:,4:8] @ rbf_b
      int cc = t-32; float s = conv_b1[cc];
      #pragma unroll
      for (int p=0;p<4;p++) s += conv_w1[cc*8+4+p]*rbf_b[p];
      wpk[288+cc] = s;
    } else if (t == 40) { // rbf quadratic-in-dd coefficients (uniform centers)
      float sig = fmaxf(expf(rbf_ls[0]), 1e-6f);
      float m = -LOG2E/(2.f*sig*sig);
      float c0 = rbf_c[0];
      float dl = rbf_c[1] - rbf_c[0];
      wpk[296] = c0;
      wpk[297] = m;
      wpk[298] = -2.f*m*dl;   // C2
      wpk[299] = m*dl*dl;     // A1
    }
  }

  const float4* f4 = (const float4*)(feat + i*16);
  float4 f0=f4[0], f1v=f4[1], f2v=f4[2], f3v=f4[3];
  const float4* w1r = (const float4*)(w1 + c*16);
  float h1 = b1[c] + d4(f0,w1r[0]) + d4(f1v,w1r[1]) + d4(f2v,w1r[2]) + d4(f3v,w1r[3]);
  h1 = leaky(h1);
  sh[w][c] = h1;
  __syncthreads();
  float hh = b2[c];
  #pragma unroll
  for (int k4=0;k4<16;k4++){
    float4 hv = *(const float4*)&sh[w][k4*4];
    hh += d4(hv, *(const float4*)&w2[c*64 + k4*4]);
  }
  hh = leaky(hh);
  h2out[i*64+c] = hh;

  float s = hh, qq = hh*hh;
  s += __shfl_xor(s,1);  qq += __shfl_xor(qq,1);
  s += __shfl_xor(s,2);  qq += __shfl_xor(qq,2);
  s += __shfl_xor(s,4);  qq += __shfl_xor(qq,4);
  s += __shfl_xor(s,8);  qq += __shfl_xor(qq,8);
  if ((c&15)==0){ int g=c>>4; sred[w][g]=s; sred[w][4+g]=qq; }
  __syncthreads();
  if (t<8) bstat1[blockIdx.x*8+t] = sred[0][t]+sred[1][t]+sred[2][t]+sred[3][t];
}

// ---------------- K2: reduce stats, group-norm, packed Q/K/V + PN ----------------
__global__ __launch_bounds__(256) void k_qkv(
  const float* __restrict__ h2b, const float* __restrict__ bstat1,
  const float* __restrict__ g_in, const float* __restrict__ be_in,
  const float* __restrict__ wq, const float* __restrict__ bq,
  const float* __restrict__ wk, const float* __restrict__ bk,
  const float* __restrict__ wv, const float* __restrict__ bv,
  const float* __restrict__ pts, const float* __restrict__ nuv,
  u32* __restrict__ Q16, u32* __restrict__ K16, u32* __restrict__ V16,
  float* __restrict__ PN)
{
  __shared__ float sh[4][64];
  __shared__ float sp[64];
  __shared__ float sst[8];
  int t=threadIdx.x, w=t>>6, c=t&63;
  int i = blockIdx.x*4 + w;
  if (t<64){ int g=t&7; float s=0.f;
    for (int m=t>>3; m<400; m+=8) s += bstat1[m*8+g];
    sp[t]=s; }
  __syncthreads();
  if (t<8){ float s=0.f;
    #pragma unroll
    for (int q=0;q<8;q++) s += sp[q*8+t];
    sst[t]=s; }
  __syncthreads();
  int g = c>>4;
  const float inv = 1.f/25600.f;
  float mu = sst[g]*inv;
  float var = sst[4+g]*inv - mu*mu;
  float rs = rsqrtf(var + 1e-5f);
  float hn = (h2b[i*64+c]-mu)*rs*g_in[c] + be_in[c];
  sh[w][c] = hn;
  __syncthreads();
  float q=bq[c], k=bk[c], v=bv[c];
  #pragma unroll
  for (int k4=0;k4<16;k4++){
    float4 hv = *(const float4*)&sh[w][k4*4];
    q += d4(hv, *(const float4*)&wq[c*64+k4*4]);
    k += d4(hv, *(const float4*)&wk[c*64+k4*4]);
    v += d4(hv, *(const float4*)&wv[c*64+k4*4]);
  }
  // packed outputs
  u16* Q16u = (u16*)Q16;
  u16* K16u = (u16*)K16;
  u16* V16u = (u16*)V16;
  __fp16 qh = (__fp16)(q*QS);
  __fp16 kh = (__fp16)k;
  __fp16 vh = (__fp16)v;
  Q16u[i*64 + c] = __builtin_bit_cast(u16, qh);
  K16u[i*64 + c] = __builtin_bit_cast(u16, kh);
  int pr = ((i>>5)<<4) + (i&15);   // pair row: (j, j+16) within 32-group
  int hf = (i>>4)&1;
  V16u[(pr*64 + c)*2 + hf] = __builtin_bit_cast(u16, vh);
  if (c < 6){
    float pv = (c<3) ? pts[i*3+c]*PSCALE : nuv[i*9+(c-3)];
    PN[i*8+c] = pv;
  } else if (c < 8) PN[i*8+c] = 0.f;
}

// ---------------- K3: all-pairs kernel — barrier-free main loop, K/V/PN direct from L2 ----------------
__global__ __launch_bounds__(256) void k_pair(
  const u32* __restrict__ Q16, const u32* __restrict__ K16, const u32* __restrict__ V16,
  const float* __restrict__ PN, const float* __restrict__ nuv,
  const float* __restrict__ w1, const float* __restrict__ wpk,
  const float* __restrict__ b2g, float* __restrict__ part)
{
  __shared__ __align__(16) float SM[4608];
  u32*   sQ16 = (u32*)SM;          // [16][36]
  u32*   sWX  = (u32*)SM + 576;    // [16][20]
  float* sRed = SM;                // [4][16][72] alias (post-loop only, behind barrier)

  int t = threadIdx.x;
  int r = t & 15, jl = t >> 4;
  int bx = blockIdx.x;
  int rb = bx % 100, jc = bx / 100;
  int I0 = rb*16, J0 = jc*CHUNKJ;
  int i = I0 + r;

  if (t < 128) { // stage Q16 tile: 16x32 u32
    int qrow = t>>3, qq4 = (t&7)<<2;
    *(uint4*)&sQ16[qrow*36+qq4] = *(const uint4*)&Q16[(I0+qrow)*32+qq4];
  }
  if (t < 128) { // wx[c][:] = conv_w1[c,0:3] @ nuv[i] ; last = conv_w1[c,3]
    int r2 = t>>3, cc = t&7, ib = (I0+r2)*9;
    float a0=w1[cc*8], a1=w1[cc*8+1], a2=w1[cc*8+2];
    float x = a0*nuv[ib+0] + a1*nuv[ib+3] + a2*nuv[ib+6];
    float y = a0*nuv[ib+1] + a1*nuv[ib+4] + a2*nuv[ib+7];
    float z = a0*nuv[ib+2] + a1*nuv[ib+5] + a2*nuv[ib+8];
    sWX[r2*20+cc*2+0] = pkn(x,y);
    sWX[r2*20+cc*2+1] = pkn(z, w1[cc*8+3]);
  }
  __syncthreads();
  u32 wxp[16];
  #pragma unroll
  for (int q2=0;q2<4;q2++) *(uint4*)&wxp[q2*4] = *(const uint4*)&sWX[r*20+q2*4];

  const u32* wp = (const u32*)wpk;
  h2 wr[8][4];
  #pragma unroll
  for (int cc=0;cc<8;cc++)
    #pragma unroll
    for (int q2=0;q2<4;q2++) wr[cc][q2] = u2h(rfl(wp[cc*4+q2]));
  const u32* w2p = wp + 32;
  const float* b1p = wpk + 288;
  float c0  = wpk[296];
  float mco = wpk[297];
  float C2  = wpk[298];
  float A1  = wpk[299];

  float4 pni0 = *(const float4*)&PN[i*8];
  float4 pni1 = *(const float4*)&PN[i*8+4];
  float pix = pni0.x, piy = pni0.y, piz = pni0.z;
  float nix = pni0.w, niy = pni1.x, niz = pni1.y;

  float acc[64];
  #pragma unroll
  for (int o=0;o<64;o++) acc[o] = 0.f;
  float lh[8];
  #pragma unroll
  for (int h=0;h<8;h++) lh[h] = 0.f;

  #pragma unroll 1
  for (int tb=0; tb<CHUNKJ; tb+=TILE) {
    int jbase = J0 + tb;
    int jA = jbase + jl;
    int jB = jA + 16;

    h2 F1p[2][4];
    float Wv[2];
    #pragma unroll
    for (int jj=0;jj<2;jj++) {
      int j = jj ? jB : jA;
      float4 a0 = *(const float4*)&PN[j*8];
      float4 a1 = *(const float4*)&PN[j*8+4];
      float dx = a0.x-pix, dy = a0.y-piy, dz = a0.z-piz;
      float ndot = nix*a0.w + niy*a1.x + niz*a1.y;
      float d2r = dx*dx + dy*dy + dz*dz;
      float wf = 2.f - ndot;
      float d2 = d2r*wf*wf;
      float tp = fmaf(d2, 0.3333333333333333f, 1.f);
      Wv[jj] = __builtin_amdgcn_rcpf(tp*tp*tp);     // (1+d2/3)^-3
      float dd = __builtin_amdgcn_sqrtf(d2);
      float g0 = dd - c0;
      float s2 = mco*g0*g0;
      float uu = C2*g0;
      float R[8];
      #pragma unroll
      for (int k=0;k<8;k++){
        float kf = (float)k, k2f = (float)(k*k);
        R[k] = __builtin_amdgcn_exp2f(fmaf(kf, uu, fmaf(k2f, A1, s2)));
      }
      h2 xv0; xv0[0]=(__fp16)dx; xv0[1]=(__fp16)dy;
      h2 xv1; xv1[0]=(__fp16)dz; xv1[1]=(__fp16)ndot;
      h2 r01=__builtin_amdgcn_cvt_pkrtz(R[0],R[1]);
      h2 r23=__builtin_amdgcn_cvt_pkrtz(R[2],R[3]);
      h2 r45=__builtin_amdgcn_cvt_pkrtz(R[4],R[5]);
      h2 r67=__builtin_amdgcn_cvt_pkrtz(R[6],R[7]);
      float F1f[8];
      #pragma unroll
      for (int cc=0;cc<8;cc++){
        float f = dot2(r67, wr[cc][3], b1p[cc]);
        f = dot2(r45, wr[cc][2], f);
        f = dot2(r23, wr[cc][1], f);
        f = dot2(r01, wr[cc][0], f);
        f = dot2(u2h(wxp[cc*2+1]), xv1, f);
        f = dot2(u2h(wxp[cc*2+0]), xv0, f);
        F1f[cc] = fmaxf(f, 0.f);
      }
      F1p[jj][0]=__builtin_amdgcn_cvt_pkrtz(F1f[0],F1f[1]);
      F1p[jj][1]=__builtin_amdgcn_cvt_pkrtz(F1f[2],F1f[3]);
      F1p[jj][2]=__builtin_amdgcn_cvt_pkrtz(F1f[4],F1f[5]);
      F1p[jj][3]=__builtin_amdgcn_cvt_pkrtz(F1f[6],F1f[7]);
    }
    h2 Wvp = __builtin_amdgcn_cvt_pkrtz(Wv[0], Wv[1]);

    const u32* kArow = &K16[jA*32];
    const u32* kBrow = &K16[jB*32];
    const u32* vrow  = &V16[(((u32)jbase>>1)+jl)*64];

    #pragma unroll
    for (int h=0;h<8;h++) {
      uint4 qh = *(const uint4*)&sQ16[r*36 + (h<<2)];
      uint4 kA = *(const uint4*)&kArow[h<<2];
      uint4 kB = *(const uint4*)&kBrow[h<<2];
      float S0 = dot2(u2h(qh.x),u2h(kA.x), dot2(u2h(qh.y),u2h(kA.y),
                 dot2(u2h(qh.z),u2h(kA.z), dot2(u2h(qh.w),u2h(kA.w), 0.f))));
      float S1 = dot2(u2h(qh.x),u2h(kB.x), dot2(u2h(qh.y),u2h(kB.y),
                 dot2(u2h(qh.z),u2h(kB.z), dot2(u2h(qh.w),u2h(kB.w), 0.f))));
      float e0 = __builtin_amdgcn_exp2f(S0);
      float e1 = __builtin_amdgcn_exp2f(S1);
      lh[h] += e0 + e1;
      h2 ewp = __builtin_amdgcn_cvt_pkrtz(e0,e1) * Wvp;
      uint4 vpA = *(const uint4*)&vrow[h*8];
      uint4 vpB = *(const uint4*)&vrow[h*8+4];
      u32 vparr[8] = {vpA.x,vpA.y,vpA.z,vpA.w,vpB.x,vpB.y,vpB.z,vpB.w};
      #pragma unroll
      for (int cc=0;cc<8;cc++){
        int rw = h*8+cc;
        h2 w0=u2h(w2p[rw*4+0]), w1h=u2h(w2p[rw*4+1]), w2h=u2h(w2p[rw*4+2]), w3h=u2h(w2p[rw*4+3]);
        float b2v = b2g[rw];
        float fh0 = dot2(F1p[0][0],w0, dot2(F1p[0][1],w1h, dot2(F1p[0][2],w2h, dot2(F1p[0][3],w3h, b2v))));
        float fh1 = dot2(F1p[1][0],w0, dot2(F1p[1][1],w1h, dot2(F1p[1][2],w2h, dot2(F1p[1][3],w3h, b2v))));
        h2 fhp = __builtin_amdgcn_cvt_pkrtz(fmaxf(fh0,0.f), fmaxf(fh1,0.f));
        h2 ev = u2h(vparr[cc]) * ewp;
        acc[rw] = dot2(fhp, ev, acc[rw]);
      }
    }
  }

  #pragma unroll
  for (int o=0;o<64;o++){ acc[o] += __shfl_xor(acc[o],16); acc[o] += __shfl_xor(acc[o],32); }
  #pragma unroll
  for (int h=0;h<8;h++){ lh[h] += __shfl_xor(lh[h],16); lh[h] += __shfl_xor(lh[h],32); }
  __syncthreads();   // protects sQ16/sWX region before sRed alias reuse
  int wv = t >> 6, lane = t & 63;
  if (lane < 16) {
    #pragma unroll
    for (int o=0;o<64;o++) sRed[(wv*16+lane)*72+o] = acc[o];
    #pragma unroll
    for (int h=0;h<8;h++) sRed[(wv*16+lane)*72+64+h] = lh[h];
  }
  __syncthreads();
  for (int v2 = t; v2 < 16*72; v2 += 256) {
    int rr = v2/72, o = v2 - rr*72;
    part[(jc*NPTS + I0 + rr)*72 + o] =
      sRed[(0*16+rr)*72+o] + sRed[(1*16+rr)*72+o] + sRed[(2*16+rr)*72+o] + sRed[(3*16+rr)*72+o];
  }
}

// ---------------- K4: merge chunk partials, divide, output MLP, out-stat partials ----------------
__global__ __launch_bounds__(256) void k_agg(
  const float* __restrict__ part, const float* __restrict__ w_o1, const float* __restrict__ b_o1,
  const float* __restrict__ w_o2, const float* __restrict__ b_o2,
  float* __restrict__ o2b, float* __restrict__ bstat2)
{
  __shared__ float sh[4][64];
  __shared__ float sred[4][8];
  int t = threadIdx.x, w = t>>6, c = t&63;
  int i = blockIdx.x*4 + w;
  int h = c>>3;
  float a = 0.f, L = 0.f;
  #pragma unroll
  for (int jc=0;jc<NCHUNK;jc++){
    const float* p = part + (jc*NPTS + i)*72;
    a += p[c]; L += p[64+h];
  }
  float agg = a / L;
  sh[w][c] = agg; __syncthreads();
  float o1 = b_o1[c];
  #pragma unroll
  for (int k4=0;k4<16;k4++){
    float4 hv = *(const float4*)&sh[w][k4*4];
    o1 += d4(hv, *(const float4*)&w_o1[c*64+k4*4]);
  }
  o1 = leaky(o1);
  __syncthreads();
  sh[w][c] = o1; __syncthreads();
  float o2 = b_o2[c];
  #pragma unroll
  for (int k4=0;k4<16;k4++){
    float4 hv = *(const float4*)&sh[w][k4*4];
    o2 += d4(hv, *(const float4*)&w_o2[c*64+k4*4]);
  }
  o2 = leaky(o2);
  o2b[i*64+c] = o2;

  float s = o2, qq = o2*o2;
  s += __shfl_xor(s,1);  qq += __shfl_xor(qq,1);
  s += __shfl_xor(s,2);  qq += __shfl_xor(qq,2);
  s += __shfl_xor(s,4);  qq += __shfl_xor(qq,4);
  s += __shfl_xor(s,8);  qq += __shfl_xor(qq,8);
  if ((c&15)==0){ int g=c>>4; sred[w][g]=s; sred[w][4+g]=qq; }
  __syncthreads();
  if (t<8) bstat2[blockIdx.x*8+t] = sred[0][t]+sred[1][t]+sred[2][t]+sred[3][t];
}

// ---------------- K5: reduce out-stats, final group-norm + residual ----------------
__global__ __launch_bounds__(256) void k_out(
  const float* __restrict__ o2b, const float* __restrict__ bstat2,
  const float* __restrict__ g_out, const float* __restrict__ be_out,
  const float* __restrict__ feat, const float* __restrict__ w_res, const float* __restrict__ b_res,
  float* __restrict__ out)
{
  __shared__ float sp[64];
  __shared__ float sst[8];
  int t = threadIdx.x, w = t>>6, c = t&63;
  int i = blockIdx.x*4 + w;
  if (t<64){ int g=t&7; float s=0.f;
    for (int m=t>>3; m<400; m+=8) s += bstat2[m*8+g];
    sp[t]=s; }
  __syncthreads();
  if (t<8){ float s=0.f;
    #pragma unroll
    for (int q=0;q<8;q++) s += sp[q*8+t];
    sst[t]=s; }
  __syncthreads();
  int g = c>>4;
  const float inv = 1.f/25600.f;
  float mu = sst[g]*inv;
  float var = sst[4+g]*inv - mu*mu;
  float rs = rsqrtf(var + 1e-5f);
  float on = (o2b[i*64+c]-mu)*rs*g_out[c] + be_out[c];
  const float4* f4 = (const float4*)(feat + i*16);
  const float4* wr = (const float4*)(w_res + c*16);
  float res = b_res[c] + d4(f4[0],wr[0]) + d4(f4[1],wr[1]) + d4(f4[2],wr[2]) + d4(f4[3],wr[3]);
  out[i*64+c] = on + res;
}

extern "C" void kernel_launch(void* const* d_in, const int* in_sizes, int n_in,
                              void* d_out, int out_size, void* d_ws, size_t ws_size,
                              hipStream_t stream) {
  const float* points  = (const float*)d_in[0];
  const float* nuv     = (const float*)d_in[1];
  const float* feat    = (const float*)d_in[2];
  const float* w_in1   = (const float*)d_in[3];
  const float* b_in1   = (const float*)d_in[4];
  const float* w_in2   = (const float*)d_in[5];
  const float* b_in2   = (const float*)d_in[6];
  const float* g_in    = (const float*)d_in[7];
  const float* be_in   = (const float*)d_in[8];
  const float* wq      = (const float*)d_in[9];
  const float* bq      = (const float*)d_in[10];
  const float* wk      = (const float*)d_in[11];
  const float* bk      = (const float*)d_in[12];
  const float* wv      = (const float*)d_in[13];
  const float* bv      = (const float*)d_in[14];
  const float* conv_w1 = (const float*)d_in[15];
  const float* conv_b1 = (const float*)d_in[16];
  const float* conv_w2 = (const float*)d_in[17];
  const float* conv_b2 = (const float*)d_in[18];
  const float* rbf_ls  = (const float*)d_in[19];
  const float* rbf_a   = (const float*)d_in[20];
  const float* rbf_b   = (const float*)d_in[21];
  const float* rbf_c   = (const float*)d_in[22];
  const float* w_o1    = (const float*)d_in[23];
  const float* b_o1    = (const float*)d_in[24];
  const float* w_o2    = (const float*)d_in[25];
  const float* b_o2    = (const float*)d_in[26];
  const float* g_out   = (const float*)d_in[27];
  const float* be_out  = (const float*)d_in[28];
  const float* w_res   = (const float*)d_in[29];
  const float* b_res   = (const float*)d_in[30];

  float* ws     = (float*)d_ws;
  float* h2f    = ws;                 // 102400
  u32*   Q16    = (u32*)(ws + 102400);// 51200 u32
  u32*   K16    = (u32*)(ws + 153600);// 51200 u32
  u32*   V16    = (u32*)(ws + 204800);// 51200 u32
  float* PN     = ws + 256000;        // 12800
  float* bstat1 = ws + 268800;        // 3200
  float* bstat2 = ws + 272000;        // 3200
  float* wpk    = ws + 275200;        // 320
  float* part   = ws + 275520;        // 1152000
  float* o2b    = ws + 1427520;       // 102400
  float* out    = (float*)d_out;

  k_in<<<400, 256, 0, stream>>>(feat, w_in1, b_in1, w_in2, b_in2,
                                conv_w1, conv_b1, conv_w2, rbf_a, rbf_b, rbf_ls, rbf_c,
                                h2f, bstat1, wpk);
  k_qkv<<<400, 256, 0, stream>>>(h2f, bstat1, g_in, be_in, wq, bq, wk, bk, wv, bv,
                                 points, nuv, Q16, K16, V16, PN);
  k_pair<<<1000, 256, 0, stream>>>(Q16, K16, V16, PN, nuv, conv_w1, wpk, conv_b2, part);
  k_agg<<<400, 256, 0, stream>>>(part, w_o1, b_o1, w_o2, b_o2, o2b, bstat2);
  k_out<<<400, 256, 0, stream>>>(o2b, bstat2, g_out, be_out, feat, w_res, b_res, out);
}